// Round 1
// baseline (201.132 us; speedup 1.0000x reference)
//
#include <hip/hip_runtime.h>
#include <hip/hip_bf16.h>
#include <stdint.h>

// Set to 0 if bench fails with absmax ~2e-3..5e-3 (older JAX "original" threefry layout)
#define JAX_PARTITIONABLE 1

// ---------------------------------------------------------------------------
// Threefry-2x32, 20 rounds (JAX-compatible)
// ---------------------------------------------------------------------------
__device__ __forceinline__ uint32_t rotl32(uint32_t v, int r) {
  return (v << r) | (v >> (32 - r));
}

__device__ __forceinline__ void threefry2x32(uint32_t k0, uint32_t k1,
                                             uint32_t x0, uint32_t x1,
                                             uint32_t& o0, uint32_t& o1) {
  uint32_t k2 = k0 ^ k1 ^ 0x1BD11BDAu;
  x0 += k0; x1 += k1;
#define TF_R(r) { x0 += x1; x1 = rotl32(x1, (r)); x1 ^= x0; }
  TF_R(13) TF_R(15) TF_R(26) TF_R(6)   x0 += k1; x1 += k2 + 1u;
  TF_R(17) TF_R(29) TF_R(16) TF_R(24)  x0 += k2; x1 += k0 + 2u;
  TF_R(13) TF_R(15) TF_R(26) TF_R(6)   x0 += k0; x1 += k1 + 3u;
  TF_R(17) TF_R(29) TF_R(16) TF_R(24)  x0 += k1; x1 += k2 + 4u;
  TF_R(13) TF_R(15) TF_R(26) TF_R(6)   x0 += k2; x1 += k0 + 5u;
#undef TF_R
  o0 = x0; o1 = x1;
}

// XLA f32 ErfInv (Giles single-precision polynomial)
__device__ __forceinline__ float erfinv_xla(float x) {
  float w = -log1pf(-x * x);
  float p;
  if (w < 5.0f) {
    w = w - 2.5f;
    p = 2.81022636e-08f;
    p = fmaf(p, w, 3.43273939e-07f);
    p = fmaf(p, w, -3.5233877e-06f);
    p = fmaf(p, w, -4.39150654e-06f);
    p = fmaf(p, w, 0.00021858087f);
    p = fmaf(p, w, -0.00125372503f);
    p = fmaf(p, w, -0.00417768164f);
    p = fmaf(p, w, 0.246640727f);
    p = fmaf(p, w, 1.50140941f);
  } else {
    w = sqrtf(w) - 3.0f;
    p = -0.000200214257f;
    p = fmaf(p, w, 0.000100950558f);
    p = fmaf(p, w, 0.00134934322f);
    p = fmaf(p, w, -0.00367342844f);
    p = fmaf(p, w, 0.00573950773f);
    p = fmaf(p, w, -0.0076224613f);
    p = fmaf(p, w, 0.00943887047f);
    p = fmaf(p, w, 1.00167406f);
    p = fmaf(p, w, 2.83297682f);
  }
  return p * x;
}

// ---------------------------------------------------------------------------
// Device globals: composite circulant kernel g[64] + derived noise key
// ---------------------------------------------------------------------------
__device__ __align__(16) float g_coeff[64];
__device__ uint32_t g_key[2];

// ---------------------------------------------------------------------------
// Setup: fold 3 rotations into one real 64-pt circulant kernel; derive noise key
// ---------------------------------------------------------------------------
__global__ void setup_kernel(const float* __restrict__ rx,
                             const float* __restrict__ ry,
                             const float* __restrict__ rz) {
  __shared__ double cre[3][64], cim[3][64];
  __shared__ double Gr[64], Gi[64];
  const int t = threadIdx.x;  // 64 threads

  if (t < 32) {
    const float* ps[3] = {rx, ry, rz};
    for (int a = 0; a < 3; ++a) {
      double s = 0.0;
      for (int r = 0; r < 16; ++r) s += (double)ps[a][t * 16 + r];
      double h = 0.5 * s;  // theta[:32] * 0.5
      double ch = cos(h), sh = sin(h);
      if (a < 2) {  // rx, ry: repeat(cos(half), 2) -> real diag
        cre[a][2 * t] = ch;     cim[a][2 * t] = 0.0;
        cre[a][2 * t + 1] = ch; cim[a][2 * t + 1] = 0.0;
      } else {      // rz: [exp(-ih), exp(+ih)] interleaved
        cre[2][2 * t] = ch;     cim[2][2 * t] = -sh;
        cre[2][2 * t + 1] = ch; cim[2][2 * t + 1] = sh;
      }
    }
  }
  __syncthreads();

  // Hermitian-symmetrize each spectrum (effect of .real between stages), product
  {
    const int k = t, kn = (64 - k) & 63;
    double pr = 1.0, pi = 0.0;
    for (int a = 0; a < 3; ++a) {
      double cr = 0.5 * (cre[a][k] + cre[a][kn]);
      double ci = 0.5 * (cim[a][k] - cim[a][kn]);
      double nr = pr * cr - pi * ci;
      double ni = pr * ci + pi * cr;
      pr = nr; pi = ni;
    }
    Gr[k] = pr; Gi[k] = pi;
  }
  __syncthreads();

  // g[m] = Re( ifft(G)[m] )
  {
    const int m = t;
    double s = 0.0;
    const double twopi_64 = 2.0 * 3.14159265358979323846 / 64.0;
    for (int k = 0; k < 64; ++k) {
      double ang = twopi_64 * (double)((k * m) & 63);
      s += Gr[k] * cos(ang) - Gi[k] * sin(ang);
    }
    g_coeff[m] = (float)(s * (1.0 / 64.0));
  }

  if (t == 0) {
    // ka = split(key(42))[0]
    uint32_t o0, o1;
#if JAX_PARTITIONABLE
    threefry2x32(0u, 42u, 0u, 0u, o0, o1);   // fold-like split, count (hi=0,lo=0)
    g_key[0] = o0; g_key[1] = o1;
#else
    uint32_t a0, a1, b0, b1;
    threefry2x32(0u, 42u, 0u, 2u, a0, a1);   // original split: counts [0,1 | 2,3]
    threefry2x32(0u, 42u, 1u, 3u, b0, b1);
    g_key[0] = a0; g_key[1] = b0;
#endif
  }
}

// ---------------------------------------------------------------------------
// Main: per (b,t) row -> circulant mix along q, JAX-exact amp noise, L2-normalize
// ---------------------------------------------------------------------------
__global__ __launch_bounds__(256) void qmain(const float* __restrict__ x,
                                             float* __restrict__ out) {
  __shared__ float Xs[4096];  // one row: [q][d], 16 KB
  __shared__ float red[8];
  const int tid = threadIdx.x;
  const int row = blockIdx.x;  // 0..4095 = b*T + t

  // stage row into LDS (coalesced float4)
  {
    const float4* xin = (const float4*)(x + (size_t)row * 4096);
    float4* xs4 = (float4*)Xs;
#pragma unroll
    for (int k = 0; k < 4; ++k) xs4[tid + k * 256] = xin[tid + k * 256];
  }

  // circulant kernel (uniform across all threads -> scalar loads)
  float G[64];
#pragma unroll
  for (int k = 0; k < 16; ++k) {
    float4 v = ((const float4*)g_coeff)[k];
    G[4 * k + 0] = v.x; G[4 * k + 1] = v.y; G[4 * k + 2] = v.z; G[4 * k + 3] = v.w;
  }
  const uint32_t ka0 = g_key[0], ka1 = g_key[1];

  __syncthreads();

  const int d = tid & 63;
  const int qb = (tid >> 6) * 16;  // this thread: q = qb..qb+15, fixed d

  float acc[16];
#pragma unroll
  for (int j = 0; j < 16; ++j) acc[j] = 0.0f;

  // y[qb+j][d] = sum_p g[(j-p)&63] * X[(qb+p)&63][d]  (compile-time g index)
#pragma unroll
  for (int p = 0; p < 64; ++p) {
    float xv = Xs[(((qb + p) & 63) << 6) + d];
#pragma unroll
    for (int j = 0; j < 16; ++j) acc[j] = fmaf(G[(j - p) & 63], xv, acc[j]);
  }

  __syncthreads();
#pragma unroll
  for (int j = 0; j < 16; ++j) Xs[((qb + j) << 6) + d] = acc[j];
  __syncthreads();

  // noise + norm over flat element index i = tid + k*256 (coalesced)
  const uint32_t base = ((uint32_t)row << 12) + (uint32_t)tid;
  float wabs[16];
  float ssum = 0.0f;
#pragma unroll
  for (int k = 0; k < 16; ++k) {
    const uint32_t idx = base + ((uint32_t)k << 8);
    uint32_t o0, o1, bits;
#if JAX_PARTITIONABLE
    threefry2x32(ka0, ka1, 0u, idx, o0, o1);
    bits = o0 ^ o1;
#else
    if (idx < (1u << 23)) { threefry2x32(ka0, ka1, idx, idx + (1u << 23), o0, o1); bits = o0; }
    else                  { threefry2x32(ka0, ka1, idx - (1u << 23), idx, o0, o1); bits = o1; }
#endif
    float f = __uint_as_float((bits >> 9) | 0x3f800000u) - 1.0f;  // [0,1)
    const float lo = -0.99999994f;  // nextafter(-1,0)
    float u = fmaxf(fmaf(f, 2.0f, lo), lo);                        // uniform(lo, 1)
    float z = 1.41421356237309515f * erfinv_xla(u);                // normal
    float amp = 0.01f * z;
    float w = (1.0f + amp) * Xs[tid + (k << 8)];
    ssum = fmaf(w, w, ssum);
    wabs[k] = fabsf(w);
  }

  // block reduction of sum of squares
#pragma unroll
  for (int off = 32; off >= 1; off >>= 1) ssum += __shfl_xor(ssum, off, 64);
  if ((tid & 63) == 0) red[tid >> 6] = ssum;
  __syncthreads();
  const float total = red[0] + red[1] + red[2] + red[3];
  const float scale = 1.0f / (sqrtf(total) + 1e-8f);

  float* orow = out + (size_t)row * 4096;
#pragma unroll
  for (int k = 0; k < 16; ++k) orow[tid + (k << 8)] = wabs[k] * scale;
}

// ---------------------------------------------------------------------------
extern "C" void kernel_launch(void* const* d_in, const int* in_sizes, int n_in,
                              void* d_out, int out_size, void* d_ws, size_t ws_size,
                              hipStream_t stream) {
  const float* x  = (const float*)d_in[0];
  const float* rx = (const float*)d_in[1];
  const float* ry = (const float*)d_in[2];
  const float* rz = (const float*)d_in[3];
  float* out = (float*)d_out;

  setup_kernel<<<1, 64, 0, stream>>>(rx, ry, rz);
  qmain<<<4096, 256, 0, stream>>>(x, out);
}

// Round 2
// 152.711 us; speedup vs baseline: 1.3171x; 1.3171x over previous
//
#include <hip/hip_runtime.h>
#include <hip/hip_bf16.h>
#include <stdint.h>

// ---------------------------------------------------------------------------
// Threefry-2x32, 20 rounds (JAX-compatible, partitionable variant)
// ---------------------------------------------------------------------------
__device__ __forceinline__ uint32_t rotl32(uint32_t v, int r) {
  return (v << r) | (v >> (32 - r));
}

__device__ __forceinline__ void threefry2x32(uint32_t k0, uint32_t k1,
                                             uint32_t x0, uint32_t x1,
                                             uint32_t& o0, uint32_t& o1) {
  uint32_t k2 = k0 ^ k1 ^ 0x1BD11BDAu;
  x0 += k0; x1 += k1;
#define TF_R(r) { x0 += x1; x1 = rotl32(x1, (r)); x1 ^= x0; }
  TF_R(13) TF_R(15) TF_R(26) TF_R(6)   x0 += k1; x1 += k2 + 1u;
  TF_R(17) TF_R(29) TF_R(16) TF_R(24)  x0 += k2; x1 += k0 + 2u;
  TF_R(13) TF_R(15) TF_R(26) TF_R(6)   x0 += k0; x1 += k1 + 3u;
  TF_R(17) TF_R(29) TF_R(16) TF_R(24)  x0 += k1; x1 += k2 + 4u;
  TF_R(13) TF_R(15) TF_R(26) TF_R(6)   x0 += k2; x1 += k0 + 5u;
#undef TF_R
  o0 = x0; o1 = x1;
}

// XLA f32 ErfInv (Giles polynomial), log1p(-x^2) replaced by hw log of
// fma(-x,x,1): max induced error in z ~1e-5 -> amp error ~1e-7 (negligible
// vs 1.7e-3 threshold; see R1 analysis).
__device__ __forceinline__ float erfinv_fast(float x) {
  float w = -__logf(fmaf(-x, x, 1.0f));
  float p;
  if (w < 5.0f) {
    w = w - 2.5f;
    p = 2.81022636e-08f;
    p = fmaf(p, w, 3.43273939e-07f);
    p = fmaf(p, w, -3.5233877e-06f);
    p = fmaf(p, w, -4.39150654e-06f);
    p = fmaf(p, w, 0.00021858087f);
    p = fmaf(p, w, -0.00125372503f);
    p = fmaf(p, w, -0.00417768164f);
    p = fmaf(p, w, 0.246640727f);
    p = fmaf(p, w, 1.50140941f);
  } else {
    w = sqrtf(w) - 3.0f;
    p = -0.000200214257f;
    p = fmaf(p, w, 0.000100950558f);
    p = fmaf(p, w, 0.00134934322f);
    p = fmaf(p, w, -0.00367342844f);
    p = fmaf(p, w, 0.00573950773f);
    p = fmaf(p, w, -0.0076224613f);
    p = fmaf(p, w, 0.00943887047f);
    p = fmaf(p, w, 1.00167406f);
    p = fmaf(p, w, 2.83297682f);
  }
  return p * x;
}

// ---------------------------------------------------------------------------
// Device globals: composite circulant kernel g[64] + derived noise key
// ---------------------------------------------------------------------------
__device__ __align__(16) float g_coeff[64];
__device__ uint32_t g_key[2];

// ---------------------------------------------------------------------------
// Setup: fold 3 rotations into one real 64-pt circulant kernel (fp32; double
// only for the 64 twiddle angles). R0's all-double version cost ~97us.
// ---------------------------------------------------------------------------
__global__ void setup_kernel(const float* __restrict__ rx,
                             const float* __restrict__ ry,
                             const float* __restrict__ rz) {
  __shared__ float cre[3][64], cim[3][64];
  __shared__ float Gr[64], Gi[64];
  __shared__ float twc[64], tws[64];
  const int t = threadIdx.x;  // 64 threads

  if (t < 32) {
    const float* ps[3] = {rx, ry, rz};
    for (int a = 0; a < 3; ++a) {
      float s = 0.0f;
      for (int r = 0; r < 16; ++r) s += ps[a][t * 16 + r];
      float h = 0.5f * s;  // theta[:32] * 0.5
      float ch = cosf(h), sh = sinf(h);
      if (a < 2) {  // rx, ry: repeat(cos(half), 2) -> real diag
        cre[a][2 * t] = ch;     cim[a][2 * t] = 0.0f;
        cre[a][2 * t + 1] = ch; cim[a][2 * t + 1] = 0.0f;
      } else {      // rz: [exp(-ih), exp(+ih)] interleaved
        cre[2][2 * t] = ch;     cim[2][2 * t] = -sh;
        cre[2][2 * t + 1] = ch; cim[2][2 * t + 1] = sh;
      }
    }
  }
  // twiddle table: only 64 double sincos on the whole grid (cheap)
  {
    double ang = (2.0 * 3.14159265358979323846 / 64.0) * (double)t;
    twc[t] = (float)cos(ang);
    tws[t] = (float)sin(ang);
  }
  __syncthreads();

  // Hermitian-symmetrize each spectrum (effect of .real between stages), product
  {
    const int k = t, kn = (64 - k) & 63;
    float pr = 1.0f, pi = 0.0f;
    for (int a = 0; a < 3; ++a) {
      float cr = 0.5f * (cre[a][k] + cre[a][kn]);
      float ci = 0.5f * (cim[a][k] - cim[a][kn]);
      float nr = pr * cr - pi * ci;
      float ni = pr * ci + pi * cr;
      pr = nr; pi = ni;
    }
    Gr[k] = pr; Gi[k] = pi;
  }
  __syncthreads();

  // g[m] = Re( ifft(G)[m] )
  {
    const int m = t;
    float s = 0.0f;
    for (int k = 0; k < 64; ++k) {
      int idx = (k * m) & 63;
      s = fmaf(Gr[k], twc[idx], s);
      s = fmaf(-Gi[k], tws[idx], s);
    }
    g_coeff[m] = s * (1.0f / 64.0f);
  }

  if (t == 0) {
    uint32_t o0, o1;
    threefry2x32(0u, 42u, 0u, 0u, o0, o1);  // ka = split(key(42))[0]
    g_key[0] = o0; g_key[1] = o1;
  }
}

// ---------------------------------------------------------------------------
// Main: per (b,t) row -> circulant mix along q, JAX-exact amp noise, L2-normalize
// ---------------------------------------------------------------------------
__global__ __launch_bounds__(256, 5) void qmain(const float* __restrict__ x,
                                                float* __restrict__ out) {
  __shared__ float Xs[4096];  // one row: [q][d], 16 KB
  __shared__ float red[4];
  const int tid = threadIdx.x;
  const int row = blockIdx.x;  // 0..4095 = b*T + t

  // stage row into LDS (coalesced float4)
  {
    const float4* xin = (const float4*)(x + (size_t)row * 4096);
    float4* xs4 = (float4*)Xs;
#pragma unroll
    for (int k = 0; k < 4; ++k) xs4[tid + k * 256] = xin[tid + k * 256];
  }

  const int d = tid & 63;
  const int qb = (tid >> 6) * 16;              // this thread: rows qb..qb+15, col d
  const int qbu = __builtin_amdgcn_readfirstlane(qb);  // provably wave-uniform

  // Rotated coefficient table: G[i] = g[(qb+i)&63]  (wave-uniform -> SGPRs).
  // Then g[(qb+j-p)&63] == G[(j-p)&63] with (j-p)&63 compile-time, and the
  // LDS reads use absolute row p -> pure immediate offsets, no addr VALU.
  float G[64];
  {
    const float4* g4 = (const float4*)g_coeff;
    const int rot = qbu >> 2;  // multiple of 4: float4-block granular rotation
#pragma unroll
    for (int k = 0; k < 16; ++k) {
      float4 v = g4[(k + rot) & 15];
      G[4 * k + 0] = v.x; G[4 * k + 1] = v.y; G[4 * k + 2] = v.z; G[4 * k + 3] = v.w;
    }
  }
  const uint32_t ka0 = g_key[0], ka1 = g_key[1];

  __syncthreads();

  float acc[16];
#pragma unroll
  for (int j = 0; j < 16; ++j) acc[j] = 0.0f;

  // y[qb+j][d] = sum_p G[(j-p)&63] * X[p][d]
#pragma unroll
  for (int p = 0; p < 64; ++p) {
    float xv = Xs[(p << 6) + d];  // offset p*256B immediate
#pragma unroll
    for (int j = 0; j < 16; ++j) acc[j] = fmaf(G[(j - p) & 63], xv, acc[j]);
  }

  __syncthreads();
#pragma unroll
  for (int j = 0; j < 16; ++j) Xs[((qb + j) << 6) + d] = acc[j];
  __syncthreads();

  // noise + norm over flat element index i = tid + k*256 (coalesced)
  const uint32_t base = ((uint32_t)row << 12) + (uint32_t)tid;
  float wabs[16];
  float ssum = 0.0f;
#pragma unroll
  for (int k = 0; k < 16; ++k) {
    const uint32_t idx = base + ((uint32_t)k << 8);
    uint32_t o0, o1;
    threefry2x32(ka0, ka1, 0u, idx, o0, o1);
    uint32_t bits = o0 ^ o1;
    float f = __uint_as_float((bits >> 9) | 0x3f800000u) - 1.0f;  // [0,1)
    const float lo = -0.99999994f;  // nextafter(-1,0)
    float u = fmaxf(fmaf(f, 2.0f, lo), lo);                        // uniform(lo,1)
    float z = 1.41421356237309515f * erfinv_fast(u);               // normal
    float w = fmaf(0.01f, z, 1.0f) * Xs[tid + (k << 8)];
    ssum = fmaf(w, w, ssum);
    wabs[k] = fabsf(w);
  }

  // block reduction of sum of squares
#pragma unroll
  for (int off = 32; off >= 1; off >>= 1) ssum += __shfl_xor(ssum, off, 64);
  if ((tid & 63) == 0) red[tid >> 6] = ssum;
  __syncthreads();
  const float total = red[0] + red[1] + red[2] + red[3];
  const float scale = 1.0f / (sqrtf(total) + 1e-8f);

  float* orow = out + (size_t)row * 4096;
#pragma unroll
  for (int k = 0; k < 16; ++k) orow[tid + (k << 8)] = wabs[k] * scale;
}

// ---------------------------------------------------------------------------
extern "C" void kernel_launch(void* const* d_in, const int* in_sizes, int n_in,
                              void* d_out, int out_size, void* d_ws, size_t ws_size,
                              hipStream_t stream) {
  const float* x  = (const float*)d_in[0];
  const float* rx = (const float*)d_in[1];
  const float* ry = (const float*)d_in[2];
  const float* rz = (const float*)d_in[3];
  float* out = (float*)d_out;

  setup_kernel<<<1, 64, 0, stream>>>(rx, ry, rz);
  qmain<<<4096, 256, 0, stream>>>(x, out);
}

// Round 3
// 142.595 us; speedup vs baseline: 1.4105x; 1.0709x over previous
//
#include <hip/hip_runtime.h>
#include <stdint.h>

typedef _Float16 half8 __attribute__((ext_vector_type(8)));
typedef float floatx4 __attribute__((ext_vector_type(4)));

// ---------------------------------------------------------------------------
// Threefry-2x32, 20 rounds (JAX-compatible, partitionable variant)
// ---------------------------------------------------------------------------
__device__ __forceinline__ uint32_t rotl32(uint32_t v, int r) {
  return (v << r) | (v >> (32 - r));
}

__device__ __forceinline__ void threefry2x32(uint32_t k0, uint32_t k1,
                                             uint32_t x0, uint32_t x1,
                                             uint32_t& o0, uint32_t& o1) {
  uint32_t k2 = k0 ^ k1 ^ 0x1BD11BDAu;
  x0 += k0; x1 += k1;
#define TF_R(r) { x0 += x1; x1 = rotl32(x1, (r)); x1 ^= x0; }
  TF_R(13) TF_R(15) TF_R(26) TF_R(6)   x0 += k1; x1 += k2 + 1u;
  TF_R(17) TF_R(29) TF_R(16) TF_R(24)  x0 += k2; x1 += k0 + 2u;
  TF_R(13) TF_R(15) TF_R(26) TF_R(6)   x0 += k0; x1 += k1 + 3u;
  TF_R(17) TF_R(29) TF_R(16) TF_R(24)  x0 += k1; x1 += k2 + 4u;
  TF_R(13) TF_R(15) TF_R(26) TF_R(6)   x0 += k2; x1 += k0 + 5u;
#undef TF_R
  o0 = x0; o1 = x1;
}

// XLA f32 ErfInv (Giles polynomial), log1p(-x^2) -> hw log of fma(-x,x,1):
// induced z error ~1e-5 -> amp error ~1e-7 (validated R2: absmax unchanged).
__device__ __forceinline__ float erfinv_fast(float x) {
  float w = -__logf(fmaf(-x, x, 1.0f));
  float p;
  if (w < 5.0f) {
    w = w - 2.5f;
    p = 2.81022636e-08f;
    p = fmaf(p, w, 3.43273939e-07f);
    p = fmaf(p, w, -3.5233877e-06f);
    p = fmaf(p, w, -4.39150654e-06f);
    p = fmaf(p, w, 0.00021858087f);
    p = fmaf(p, w, -0.00125372503f);
    p = fmaf(p, w, -0.00417768164f);
    p = fmaf(p, w, 0.246640727f);
    p = fmaf(p, w, 1.50140941f);
  } else {
    w = sqrtf(w) - 3.0f;
    p = -0.000200214257f;
    p = fmaf(p, w, 0.000100950558f);
    p = fmaf(p, w, 0.00134934322f);
    p = fmaf(p, w, -0.00367342844f);
    p = fmaf(p, w, 0.00573950773f);
    p = fmaf(p, w, -0.0076224613f);
    p = fmaf(p, w, 0.00943887047f);
    p = fmaf(p, w, 1.00167406f);
    p = fmaf(p, w, 2.83297682f);
  }
  return p * x;
}

// ---------------------------------------------------------------------------
// Device globals: reversed+duplicated circulant kernel (f16) + noise key
// grevh2[i] = (f16) g[(64 - i) & 63], duplicated to 128 so any 8-elem window
// starting at s<=63 reads without mod-wrap.
// ---------------------------------------------------------------------------
__device__ __align__(16) _Float16 grevh2[128];
__device__ uint32_t g_key[2];

// ---------------------------------------------------------------------------
// Setup: fold 3 rotations into one real 64-pt circulant kernel (fp32; double
// only for the 64 twiddle angles), emit reversed f16 table + threefry key.
// ---------------------------------------------------------------------------
__global__ void setup_kernel(const float* __restrict__ rx,
                             const float* __restrict__ ry,
                             const float* __restrict__ rz) {
  __shared__ float cre[3][64], cim[3][64];
  __shared__ float Gr[64], Gi[64];
  __shared__ float twc[64], tws[64];
  __shared__ float gs[64];
  const int t = threadIdx.x;  // 64 threads

  if (t < 32) {
    const float* ps[3] = {rx, ry, rz};
    for (int a = 0; a < 3; ++a) {
      float s = 0.0f;
      for (int r = 0; r < 16; ++r) s += ps[a][t * 16 + r];
      float h = 0.5f * s;  // theta[:32] * 0.5
      float ch = cosf(h), sh = sinf(h);
      if (a < 2) {  // rx, ry: repeat(cos(half), 2) -> real diag
        cre[a][2 * t] = ch;     cim[a][2 * t] = 0.0f;
        cre[a][2 * t + 1] = ch; cim[a][2 * t + 1] = 0.0f;
      } else {      // rz: [exp(-ih), exp(+ih)] interleaved
        cre[2][2 * t] = ch;     cim[2][2 * t] = -sh;
        cre[2][2 * t + 1] = ch; cim[2][2 * t + 1] = sh;
      }
    }
  }
  {
    double ang = (2.0 * 3.14159265358979323846 / 64.0) * (double)t;
    twc[t] = (float)cos(ang);
    tws[t] = (float)sin(ang);
  }
  __syncthreads();

  // Hermitian-symmetrize each spectrum (effect of .real between stages), product
  {
    const int k = t, kn = (64 - k) & 63;
    float pr = 1.0f, pi = 0.0f;
    for (int a = 0; a < 3; ++a) {
      float cr = 0.5f * (cre[a][k] + cre[a][kn]);
      float ci = 0.5f * (cim[a][k] - cim[a][kn]);
      float nr = pr * cr - pi * ci;
      float ni = pr * ci + pi * cr;
      pr = nr; pi = ni;
    }
    Gr[k] = pr; Gi[k] = pi;
  }
  __syncthreads();

  // g[m] = Re( ifft(G)[m] )
  {
    const int mi = t;
    float s = 0.0f;
    for (int k = 0; k < 64; ++k) {
      int idx = (k * mi) & 63;
      s = fmaf(Gr[k], twc[idx], s);
      s = fmaf(-Gi[k], tws[idx], s);
    }
    gs[mi] = s * (1.0f / 64.0f);
  }
  __syncthreads();

  {
    _Float16 hv = (_Float16)gs[(64 - t) & 63];
    grevh2[t] = hv;
    grevh2[t + 64] = hv;
  }

  if (t == 0) {
    uint32_t o0, o1;
    threefry2x32(0u, 42u, 0u, 0u, o0, o1);  // ka = split(key(42))[0]
    g_key[0] = o0; g_key[1] = o1;
  }
}

// ---------------------------------------------------------------------------
// Main: per (b,t) row. Circulant Y = Gm . X as f16 MFMA (fp32 accum), then
// JAX-exact amp noise + L2-normalize computed directly on MFMA C-layout.
//   A[m][k]  = Gm[16w+m][k] = grevh2[(k - 16w - m) & 63], m=lane&15, k=quad*8+j
//   B[k][n]  = X[k][16c+n]  -> transposed f16 LDS Xt[d][q], 1 ds_read_b128/frag
//   D[r][n]  : col=lane&15, row=quad*4+reg (verified layout)
// ---------------------------------------------------------------------------
__global__ __launch_bounds__(256, 5) void qmain(const float* __restrict__ x,
                                                float* __restrict__ out) {
  __shared__ __align__(16) _Float16 Xt[64 * 72];  // [d][q], row stride 72 halfs
  __shared__ float red[4];
  const int tid = threadIdx.x;
  const int row = blockIdx.x;  // 0..4095 = b*T + t
  const int lane = tid & 63;
  const int w = tid >> 6;      // wave id: output rows 16w..16w+15
  const int quad = lane >> 4;  // 0..3
  const int m = lane & 15;     // A's m index == D's col index

  // A fragments (global u16 loads, start early to hide latency)
  half8 af0, af1;
  {
    const int s0 = (8 * quad - 16 * w - m) & 63;
    const int s1 = (32 + 8 * quad - 16 * w - m) & 63;
#pragma unroll
    for (int j = 0; j < 8; ++j) af0[j] = grevh2[s0 + j];
#pragma unroll
    for (int j = 0; j < 8; ++j) af1[j] = grevh2[s1 + j];
  }
  const uint32_t ka0 = g_key[0], ka1 = g_key[1];

  // stage row -> Xt (cvt f16 + transpose), pair-packed b32 writes
  {
    const float* xr = x + (size_t)row * 4096;
    const int tq = tid >> 4;         // 0..15
    const int d0 = (tid & 15) * 4;   // 0..60
#pragma unroll
    for (int u = 0; u < 2; ++u) {
      const int q0 = 2 * tq + 32 * u;
      float4 a = *(const float4*)(xr + q0 * 64 + d0);
      float4 b = *(const float4*)(xr + (q0 + 1) * 64 + d0);
      const float av[4] = {a.x, a.y, a.z, a.w};
      const float bv[4] = {b.x, b.y, b.z, b.w};
#pragma unroll
      for (int i = 0; i < 4; ++i) {
        union { _Float16 h[2]; uint32_t u32; } pk;
        pk.h[0] = (_Float16)av[i];   // Xt[d0+i][q0]
        pk.h[1] = (_Float16)bv[i];   // Xt[d0+i][q0+1]
        *(uint32_t*)&Xt[(d0 + i) * 72 + q0] = pk.u32;
      }
    }
  }
  __syncthreads();

  // 8 MFMAs: acc[c] covers Y[16w+4quad+r][16c+m]
  floatx4 acc[4];
#pragma unroll
  for (int c = 0; c < 4; ++c) {
    const _Float16* bp = &Xt[(16 * c + m) * 72 + 8 * quad];
    half8 b0 = *(const half8*)bp;          // k = 0..31 slice
    half8 b1 = *(const half8*)(bp + 32);   // k = 32..63 slice
    acc[c] = (floatx4){0.0f, 0.0f, 0.0f, 0.0f};
    acc[c] = __builtin_amdgcn_mfma_f32_16x16x32_f16(af0, b0, acc[c], 0, 0, 0);
    acc[c] = __builtin_amdgcn_mfma_f32_16x16x32_f16(af1, b1, acc[c], 0, 0, 0);
  }

  // noise + sum of squares, directly on C-layout elements
  // element (c, r): (q, d) = (16w + 4quad + r, 16c + m)
  const uint32_t idxbase = ((uint32_t)row << 12) + (uint32_t)(((16 * w + 4 * quad) << 6) + m);
  float wabs[16];
  float ssum = 0.0f;
#pragma unroll
  for (int c = 0; c < 4; ++c) {
#pragma unroll
    for (int r = 0; r < 4; ++r) {
      const uint32_t idx = idxbase + (uint32_t)(r * 64 + 16 * c);
      uint32_t o0, o1;
      threefry2x32(ka0, ka1, 0u, idx, o0, o1);
      uint32_t bits = o0 ^ o1;
      float f = __uint_as_float((bits >> 9) | 0x3f800000u) - 1.0f;  // [0,1)
      const float lo = -0.99999994f;  // nextafter(-1,0)
      float u = fmaxf(fmaf(f, 2.0f, lo), lo);                        // uniform(lo,1)
      float z = 1.41421356237309515f * erfinv_fast(u);               // normal
      float wv = fmaf(0.01f, z, 1.0f) * acc[c][r];
      ssum = fmaf(wv, wv, ssum);
      wabs[c * 4 + r] = fabsf(wv);
    }
  }

  // block reduction of sum of squares
#pragma unroll
  for (int off = 32; off >= 1; off >>= 1) ssum += __shfl_xor(ssum, off, 64);
  if (lane == 0) red[w] = ssum;
  __syncthreads();
  const float total = red[0] + red[1] + red[2] + red[3];
  const float scale = 1.0f / (sqrtf(total) + 1e-8f);

  // stores: one base VGPR pair + 16 immediate-offset dword stores
  float* ob = out + (size_t)row * 4096 + (size_t)(((16 * w + 4 * quad) << 6) + m);
#pragma unroll
  for (int c = 0; c < 4; ++c)
#pragma unroll
    for (int r = 0; r < 4; ++r)
      ob[r * 64 + 16 * c] = wabs[c * 4 + r] * scale;
}

// ---------------------------------------------------------------------------
extern "C" void kernel_launch(void* const* d_in, const int* in_sizes, int n_in,
                              void* d_out, int out_size, void* d_ws, size_t ws_size,
                              hipStream_t stream) {
  const float* x  = (const float*)d_in[0];
  const float* rx = (const float*)d_in[1];
  const float* ry = (const float*)d_in[2];
  const float* rz = (const float*)d_in[3];
  float* out = (float*)d_out;

  setup_kernel<<<1, 64, 0, stream>>>(rx, ry, rz);
  qmain<<<4096, 256, 0, stream>>>(x, out);
}

// Round 6
// 141.027 us; speedup vs baseline: 1.4262x; 1.0111x over previous
//
#include <hip/hip_runtime.h>
#include <stdint.h>

typedef _Float16 half8 __attribute__((ext_vector_type(8)));
typedef float floatx4 __attribute__((ext_vector_type(4)));

// ---------------------------------------------------------------------------
// Threefry-2x32, 20 rounds (JAX-compatible, partitionable variant)
// ---------------------------------------------------------------------------
__device__ __forceinline__ uint32_t rotl32(uint32_t v, int r) {
  return (v << r) | (v >> (32 - r));
}

__device__ __forceinline__ void threefry2x32(uint32_t k0, uint32_t k1,
                                             uint32_t x0, uint32_t x1,
                                             uint32_t& o0, uint32_t& o1) {
  uint32_t k2 = k0 ^ k1 ^ 0x1BD11BDAu;
  x0 += k0; x1 += k1;
#define TF_R(r) { x0 += x1; x1 = rotl32(x1, (r)); x1 ^= x0; }
  TF_R(13) TF_R(15) TF_R(26) TF_R(6)   x0 += k1; x1 += k2 + 1u;
  TF_R(17) TF_R(29) TF_R(16) TF_R(24)  x0 += k2; x1 += k0 + 2u;
  TF_R(13) TF_R(15) TF_R(26) TF_R(6)   x0 += k0; x1 += k1 + 3u;
  TF_R(17) TF_R(29) TF_R(16) TF_R(24)  x0 += k1; x1 += k2 + 4u;
  TF_R(13) TF_R(15) TF_R(26) TF_R(6)   x0 += k2; x1 += k0 + 5u;
#undef TF_R
  o0 = x0; o1 = x1;
}

// XLA f32 ErfInv (Giles polynomial); log1p(-x^2) -> hw log (validated R2/R3).
// NOTE (R4 NaN post-mortem): caller MUST clamp u > -1; u = -1.0 exactly gives
// log(0) -> -inf -> erfinv = -inf -> NaN through the norm. Happens when the
// threefry mantissa bits are all zero (~2 hits in 16.7M samples).
__device__ __forceinline__ float erfinv_fast(float x) {
  float w = -__logf(fmaf(-x, x, 1.0f));
  float p;
  if (__builtin_expect(w >= 5.0f, 0)) {
    w = sqrtf(w) - 3.0f;
    p = -0.000200214257f;
    p = fmaf(p, w, 0.000100950558f);
    p = fmaf(p, w, 0.00134934322f);
    p = fmaf(p, w, -0.00367342844f);
    p = fmaf(p, w, 0.00573950773f);
    p = fmaf(p, w, -0.0076224613f);
    p = fmaf(p, w, 0.00943887047f);
    p = fmaf(p, w, 1.00167406f);
    p = fmaf(p, w, 2.83297682f);
  } else {
    w = w - 2.5f;
    p = 2.81022636e-08f;
    p = fmaf(p, w, 3.43273939e-07f);
    p = fmaf(p, w, -3.5233877e-06f);
    p = fmaf(p, w, -4.39150654e-06f);
    p = fmaf(p, w, 0.00021858087f);
    p = fmaf(p, w, -0.00125372503f);
    p = fmaf(p, w, -0.00417768164f);
    p = fmaf(p, w, 0.246640727f);
    p = fmaf(p, w, 1.50140941f);
  }
  return p * x;
}

// ---------------------------------------------------------------------------
// Device globals: precomputed per-tid A fragments (f16) + noise key
// g_afrag[tid][16]: halfs 0..7 = af0 (k=0..31 slice), 8..15 = af1 (k=32..63)
// ---------------------------------------------------------------------------
__device__ __align__(16) _Float16 g_afrag[256 * 16];
__device__ uint32_t g_key[2];

// ---------------------------------------------------------------------------
// Setup: fold 3 rotations into one real 64-pt circulant kernel g[64] (fp32,
// double only for twiddles), then emit per-tid MFMA A-fragments + threefry key.
// ---------------------------------------------------------------------------
__global__ void setup_kernel(const float* __restrict__ rx,
                             const float* __restrict__ ry,
                             const float* __restrict__ rz) {
  __shared__ float cre[3][64], cim[3][64];
  __shared__ float Gr[64], Gi[64];
  __shared__ float twc[64], tws[64];
  __shared__ float gs[64];
  const int t = threadIdx.x;  // 256 threads

  if (t < 32) {
    const float* ps[3] = {rx, ry, rz};
    for (int a = 0; a < 3; ++a) {
      float s = 0.0f;
      for (int r = 0; r < 16; ++r) s += ps[a][t * 16 + r];
      float h = 0.5f * s;  // theta[:32] * 0.5
      float ch = cosf(h), sh = sinf(h);
      if (a < 2) {  // rx, ry: repeat(cos(half), 2) -> real diag
        cre[a][2 * t] = ch;     cim[a][2 * t] = 0.0f;
        cre[a][2 * t + 1] = ch; cim[a][2 * t + 1] = 0.0f;
      } else {      // rz: [exp(-ih), exp(+ih)] interleaved
        cre[2][2 * t] = ch;     cim[2][2 * t] = -sh;
        cre[2][2 * t + 1] = ch; cim[2][2 * t + 1] = sh;
      }
    }
  }
  if (t < 64) {
    double ang = (2.0 * 3.14159265358979323846 / 64.0) * (double)t;
    twc[t] = (float)cos(ang);
    tws[t] = (float)sin(ang);
  }
  __syncthreads();

  if (t < 64) {  // Hermitian-symmetrize each spectrum, complex product
    const int k = t, kn = (64 - k) & 63;
    float pr = 1.0f, pi = 0.0f;
    for (int a = 0; a < 3; ++a) {
      float cr = 0.5f * (cre[a][k] + cre[a][kn]);
      float ci = 0.5f * (cim[a][k] - cim[a][kn]);
      float nr = pr * cr - pi * ci;
      float ni = pr * ci + pi * cr;
      pr = nr; pi = ni;
    }
    Gr[k] = pr; Gi[k] = pi;
  }
  __syncthreads();

  if (t < 64) {  // g[m] = Re( ifft(G)[m] )
    const int mi = t;
    float s = 0.0f;
    for (int k = 0; k < 64; ++k) {
      int idx = (k * mi) & 63;
      s = fmaf(Gr[k], twc[idx], s);
      s = fmaf(-Gi[k], tws[idx], s);
    }
    gs[mi] = s * (1.0f / 64.0f);
  }
  __syncthreads();

  // A[row][k] = g[(row - k)&63] for row = 16w+m, k = 8*quad + j (+32 for af1).
  // R5 post-mortem: this was g[(k-row)&63] (transposed circulant => absmax
  // 7.8e-2, the odd part of g). Convolution, not correlation.
  {
    const int w = t >> 6, lane = t & 63, quad = lane >> 4, m = lane & 15;
    const int r0 = 16 * w + m - 8 * quad;
#pragma unroll
    for (int j = 0; j < 8; ++j) {
      g_afrag[t * 16 + j]     = (_Float16)gs[(r0 - j) & 63];
      g_afrag[t * 16 + 8 + j] = (_Float16)gs[(r0 - 32 - j) & 63];
    }
  }

  if (t == 0) {
    uint32_t o0, o1;
    threefry2x32(0u, 42u, 0u, 0u, o0, o1);  // ka = split(key(42))[0]
    g_key[0] = o0; g_key[1] = o1;
  }
}

// ---------------------------------------------------------------------------
// Main: per (b,t) row. Y = Gm . X via f16 MFMA (fp32 accum); JAX-exact amp
// noise + L2-normalize directly on MFMA C-layout (col=lane&15, row=quad*4+r).
// Transpose staging: float2-over-d x 8q per thread -> 2 x ds_write_b128.
// (Write lane stride = 72 dw == 8 banks -> 2-way phase conflict; cost ~0.26M
// cycles total ~1% — accepted, not worth a swizzle that would misalign reads.)
// ---------------------------------------------------------------------------
__global__ __launch_bounds__(256, 8) void qmain(const float* __restrict__ x,
                                                float* __restrict__ out) {
  __shared__ __align__(16) _Float16 Xt[64 * 72];  // [d][q], row stride 72 halfs
  __shared__ float red[4];
  const int tid = threadIdx.x;
  const int row = blockIdx.x;  // 0..4095 = b*T + t
  const int lane = tid & 63;
  const int w = tid >> 6;      // wave id: output rows 16w..16w+15
  const int quad = lane >> 4;  // 0..3
  const int m = lane & 15;     // A's m index == D's col index

  // A fragments: 2 coalesced 16B loads from the precomputed table
  const half8* at = (const half8*)g_afrag;
  half8 af0 = at[2 * tid];
  half8 af1 = at[2 * tid + 1];
  const uint32_t ka0 = g_key[0], ka1 = g_key[1];

  // stage row -> Xt (cvt f16 + transpose in registers)
  {
    const float* xr = x + (size_t)row * 4096;
    const int d0 = (tid & 31) * 2;   // this thread: d rows d0, d0+1
    const int q0 = (tid >> 5) * 8;   // q columns q0..q0+7
    float2 v[8];
#pragma unroll
    for (int s = 0; s < 8; ++s) v[s] = *(const float2*)(xr + (q0 + s) * 64 + d0);
    union { _Float16 h[8]; uint4 u; } r0, r1;
#pragma unroll
    for (int s = 0; s < 8; ++s) { r0.h[s] = (_Float16)v[s].x; r1.h[s] = (_Float16)v[s].y; }
    *(uint4*)&Xt[d0 * 72 + q0] = r0.u;        // 16B-aligned b128 writes
    *(uint4*)&Xt[(d0 + 1) * 72 + q0] = r1.u;
  }
  __syncthreads();

  // 8 MFMAs: acc[c] covers Y[16w+4quad+r][16c+m]
  floatx4 acc[4];
#pragma unroll
  for (int c = 0; c < 4; ++c) {
    const _Float16* bp = &Xt[(16 * c + m) * 72 + 8 * quad];
    half8 b0 = *(const half8*)bp;          // k = 0..31 slice
    half8 b1 = *(const half8*)(bp + 32);   // k = 32..63 slice
    acc[c] = (floatx4){0.0f, 0.0f, 0.0f, 0.0f};
    acc[c] = __builtin_amdgcn_mfma_f32_16x16x32_f16(af0, b0, acc[c], 0, 0, 0);
    acc[c] = __builtin_amdgcn_mfma_f32_16x16x32_f16(af1, b1, acc[c], 0, 0, 0);
  }

  // noise + sum of squares, directly on C-layout elements
  // element (c, r): (q, d) = (16w + 4quad + r, 16c + m)
  const uint32_t idxbase = ((uint32_t)row << 12) + (uint32_t)(((16 * w + 4 * quad) << 6) + m);
  float wv[16];
  float ssum = 0.0f;
#pragma unroll
  for (int c = 0; c < 4; ++c) {
#pragma unroll
    for (int r = 0; r < 4; ++r) {
      const uint32_t idx = idxbase + (uint32_t)(r * 64 + 16 * c);
      uint32_t o0, o1;
      threefry2x32(ka0, ka1, 0u, idx, o0, o1);
      uint32_t bits = o0 ^ o1;
      float vf = __uint_as_float((bits >> 9) | 0x3f800000u);   // [1,2)
      // u = 2*vf - 3 clamped to lo = -(1-2^-24); clamp is REQUIRED (R4: u=-1
      // -> erfinv(-1) = -inf -> NaN). Matches JAX's maximum(minval, ...).
      float u = fmaxf(fmaf(vf, 2.0f, -3.0f), -0.99999994f);
      // (1 + 0.01*sqrt(2)*erfinv(u)) * y
      float val = fmaf(erfinv_fast(u), 0.014142135623730951f, 1.0f) * acc[c][r];
      ssum = fmaf(val, val, ssum);
      wv[c * 4 + r] = val;
    }
  }

  // block reduction of sum of squares
#pragma unroll
  for (int off = 32; off >= 1; off >>= 1) ssum += __shfl_xor(ssum, off, 64);
  if (lane == 0) red[w] = ssum;
  __syncthreads();
  const float total = red[0] + red[1] + red[2] + red[3];
  const float scale = 1.0f / (sqrtf(total) + 1e-8f);

  // stores: one base + 16 immediate-offset dword stores (|.| folds into v_mul)
  float* ob = out + (size_t)row * 4096 + (size_t)(((16 * w + 4 * quad) << 6) + m);
#pragma unroll
  for (int c = 0; c < 4; ++c)
#pragma unroll
    for (int r = 0; r < 4; ++r)
      ob[r * 64 + 16 * c] = fabsf(wv[c * 4 + r]) * scale;
}

// ---------------------------------------------------------------------------
extern "C" void kernel_launch(void* const* d_in, const int* in_sizes, int n_in,
                              void* d_out, int out_size, void* d_ws, size_t ws_size,
                              hipStream_t stream) {
  const float* x  = (const float*)d_in[0];
  const float* rx = (const float*)d_in[1];
  const float* ry = (const float*)d_in[2];
  const float* rz = (const float*)d_in[3];
  float* out = (float*)d_out;

  setup_kernel<<<1, 256, 0, stream>>>(rx, ry, rz);
  qmain<<<4096, 256, 0, stream>>>(x, out);
}